// Round 1
// baseline (1278.996 us; speedup 1.0000x reference)
//
#include <hip/hip_runtime.h>
#include <math.h>

#define H 8
#define FD 128
#define SCALE 0.25f

// ---- monotonic float<->uint mapping for atomicMax on floats ----
__device__ __forceinline__ unsigned enc_f(float f) {
    unsigned u = __float_as_uint(f);
    return (u & 0x80000000u) ? ~u : (u | 0x80000000u);
}
__device__ __forceinline__ float dec_f(unsigned u) {
    return (u & 0x80000000u) ? __uint_as_float(u ^ 0x80000000u)
                             : __uint_as_float(~u);
}

// Load W[128][128] into LDS with a 4-col rotation swizzle:
// W[i][j] stored at Wl[i*128 + ((j + 4*(i>>2)) & 127)]
// so that reads of rows 4*fe+c (fe = lane) spread across all 32 banks.
__device__ __forceinline__ void load_w_lds(const float* __restrict__ W,
                                           float* Wl, int tid) {
    for (int x = tid; x < (FD * FD) / 4; x += 256) {
        int idx4 = x << 2;
        int i = idx4 >> 7;
        int j = idx4 & 127;
        float4 w = *(const float4*)(W + idx4);
        int col = (j + ((i >> 2) << 2)) & 127;
        *(float4*)(Wl + i * FD + col) = w;
    }
}

// out[r,i] = sum_j X[r,j]*W[i,j] + b[i]   (X: [Nrows,128], W: [128,128])
__global__ __launch_bounds__(256) void proj_kernel(
    const float* __restrict__ X, const float* __restrict__ W,
    const float* __restrict__ b, float* __restrict__ out, int Nrows) {
    __shared__ float Wl[FD * FD];
    int tid = threadIdx.x;
    load_w_lds(W, Wl, tid);
    __syncthreads();

    int fe = tid & 31;   // feature quad: handles features 4*fe..4*fe+3
    int te = tid >> 5;   // row slice
    int row0 = blockIdx.x * 64;

    float4 bias = *(const float4*)(b + 4 * fe);
    float acc[8][4];
#pragma unroll
    for (int u = 0; u < 8; ++u) {
        acc[u][0] = bias.x; acc[u][1] = bias.y;
        acc[u][2] = bias.z; acc[u][3] = bias.w;
    }
    const float* Ar[8];
#pragma unroll
    for (int u = 0; u < 8; ++u) {
        int r = row0 + te + 8 * u;
        if (r >= Nrows) r = Nrows - 1;
        Ar[u] = X + (size_t)r * FD;
    }
    for (int j = 0; j < FD; j += 4) {
        int g = (j + 4 * fe) & 127;
        float4 w0 = *(float4*)(Wl + (4 * fe + 0) * FD + g);
        float4 w1 = *(float4*)(Wl + (4 * fe + 1) * FD + g);
        float4 w2 = *(float4*)(Wl + (4 * fe + 2) * FD + g);
        float4 w3 = *(float4*)(Wl + (4 * fe + 3) * FD + g);
#pragma unroll
        for (int u = 0; u < 8; ++u) {
            float4 a = *(const float4*)(Ar[u] + j);
            acc[u][0] += a.x * w0.x + a.y * w0.y + a.z * w0.z + a.w * w0.w;
            acc[u][1] += a.x * w1.x + a.y * w1.y + a.z * w1.z + a.w * w1.w;
            acc[u][2] += a.x * w2.x + a.y * w2.y + a.z * w2.z + a.w * w2.w;
            acc[u][3] += a.x * w3.x + a.y * w3.y + a.z * w3.z + a.w * w3.w;
        }
    }
#pragma unroll
    for (int u = 0; u < 8; ++u) {
        int r = row0 + te + 8 * u;
        if (r < Nrows) {
            float4 o;
            o.x = acc[u][0]; o.y = acc[u][1]; o.z = acc[u][2]; o.w = acc[u][3];
            *(float4*)(out + (size_t)r * FD + 4 * fe) = o;
        }
    }
}

// Fused: k[e] = Wk@edge_h[e]+bk (kept in regs), then
// l1 = (q[src].k)*S, l2 = (q[dst].k)*S, l3 = (q[src].q[dst])*S,
// plus atomicMax segment maxima per (dst, head).
__global__ __launch_bounds__(256) void edge_kernel(
    const float* __restrict__ eh, const float* __restrict__ Wk,
    const float* __restrict__ bk, const float* __restrict__ q,
    const int* __restrict__ src, const int* __restrict__ dst,
    float* __restrict__ l1, float* __restrict__ l2, float* __restrict__ l3,
    unsigned* __restrict__ m1, unsigned* __restrict__ m2,
    unsigned* __restrict__ m3, int E) {
    __shared__ float Wl[FD * FD];
    int tid = threadIdx.x;
    load_w_lds(Wk, Wl, tid);
    __syncthreads();

    int fe = tid & 31;
    int te = tid >> 5;
    int e0 = blockIdx.x * 64;

    float4 bias = *(const float4*)(bk + 4 * fe);
    float acc[8][4];
#pragma unroll
    for (int u = 0; u < 8; ++u) {
        acc[u][0] = bias.x; acc[u][1] = bias.y;
        acc[u][2] = bias.z; acc[u][3] = bias.w;
    }
    const float* Ar[8];
    int ev[8];
#pragma unroll
    for (int u = 0; u < 8; ++u) {
        int e = e0 + te + 8 * u;
        ev[u] = e;
        int ec = (e < E) ? e : (E - 1);
        Ar[u] = eh + (size_t)ec * FD;
    }
    for (int j = 0; j < FD; j += 4) {
        int g = (j + 4 * fe) & 127;
        float4 w0 = *(float4*)(Wl + (4 * fe + 0) * FD + g);
        float4 w1 = *(float4*)(Wl + (4 * fe + 1) * FD + g);
        float4 w2 = *(float4*)(Wl + (4 * fe + 2) * FD + g);
        float4 w3 = *(float4*)(Wl + (4 * fe + 3) * FD + g);
#pragma unroll
        for (int u = 0; u < 8; ++u) {
            float4 a = *(const float4*)(Ar[u] + j);
            acc[u][0] += a.x * w0.x + a.y * w0.y + a.z * w0.z + a.w * w0.w;
            acc[u][1] += a.x * w1.x + a.y * w1.y + a.z * w1.z + a.w * w1.w;
            acc[u][2] += a.x * w2.x + a.y * w2.y + a.z * w2.z + a.w * w2.w;
            acc[u][3] += a.x * w3.x + a.y * w3.y + a.z * w3.z + a.w * w3.w;
        }
    }
    int h = fe >> 2;  // head for features 4*fe..4*fe+3
#pragma unroll
    for (int u = 0; u < 8; ++u) {
        int e = ev[u];
        if (e >= E) continue;  // uniform across the 4-lane head group
        int sidx = src[e], didx = dst[e];
        float4 qs = *(const float4*)(q + (size_t)sidx * FD + 4 * fe);
        float4 qd = *(const float4*)(q + (size_t)didx * FD + 4 * fe);
        float pin = qs.x * acc[u][0] + qs.y * acc[u][1] +
                    qs.z * acc[u][2] + qs.w * acc[u][3];
        float pot = qd.x * acc[u][0] + qd.y * acc[u][1] +
                    qd.z * acc[u][2] + qd.w * acc[u][3];
        float pdg = qs.x * qd.x + qs.y * qd.y + qs.z * qd.z + qs.w * qd.w;
        pin += __shfl_xor(pin, 1); pin += __shfl_xor(pin, 2);
        pot += __shfl_xor(pot, 1); pot += __shfl_xor(pot, 2);
        pdg += __shfl_xor(pdg, 1); pdg += __shfl_xor(pdg, 2);
        if ((fe & 3) == 0) {
            size_t oi = (size_t)e * H + h;
            int nb = didx * H + h;
            float a1 = pin * SCALE, a2 = pot * SCALE, a3 = pdg * SCALE;
            l1[oi] = a1; l2[oi] = a2; l3[oi] = a3;
            atomicMax(m1 + nb, enc_f(a1));
            atomicMax(m2 + nb, enc_f(a2));
            atomicMax(m3 + nb, enc_f(a3));
        }
    }
}

__global__ __launch_bounds__(256) void den_kernel(
    const float* __restrict__ l1, const float* __restrict__ l2,
    const float* __restrict__ l3, const unsigned* __restrict__ m1,
    const unsigned* __restrict__ m2, const unsigned* __restrict__ m3,
    const int* __restrict__ dst, float* __restrict__ den1,
    float* __restrict__ den2, float* __restrict__ den3, int EH) {
    int idx = blockIdx.x * 256 + threadIdx.x;
    if (idx >= EH) return;
    int e = idx >> 3, h = idx & 7;
    int nb = dst[e] * H + h;
    atomicAdd(den1 + nb, __expf(l1[idx] - dec_f(m1[nb])));
    atomicAdd(den2 + nb, __expf(l2[idx] - dec_f(m2[nb])));
    atomicAdd(den3 + nb, __expf(l3[idx] - dec_f(m3[nb])));
}

__global__ __launch_bounds__(256) void score_kernel(
    const float* __restrict__ l1, const float* __restrict__ l2,
    const float* __restrict__ l3, const unsigned* __restrict__ m1,
    const unsigned* __restrict__ m2, const unsigned* __restrict__ m3,
    const float* __restrict__ den1, const float* __restrict__ den2,
    const float* __restrict__ den3, const int* __restrict__ dst,
    const float* __restrict__ distance, const float* __restrict__ lam,
    float* __restrict__ ssum, int EH) {
    int idx = blockIdx.x * 256 + threadIdx.x;
    if (idx >= EH) return;
    int e = idx >> 3, h = idx & 7;
    int nb = dst[e] * H + h;
    float att = __powf(distance[e], lam[0]);
    float sc = (__expf(l1[idx] - dec_f(m1[nb])) / den1[nb] +
                __expf(l2[idx] - dec_f(m2[nb])) / den2[nb] +
                __expf(l3[idx] - dec_f(m3[nb])) / den3[nb]) * att;
    atomicAdd(ssum + nb, sc);
}

// out[n,i] = leaky_relu( sum_j (ssum[n, j/16]*v[n,j]) * Wo[i,j] + bo[i] )
__global__ __launch_bounds__(256) void out_kernel(
    const float* __restrict__ v, const float* __restrict__ ssum,
    const float* __restrict__ Wo, const float* __restrict__ bo,
    float* __restrict__ out, int Nrows) {
    __shared__ float Wl[FD * FD];
    int tid = threadIdx.x;
    load_w_lds(Wo, Wl, tid);
    __syncthreads();

    int fe = tid & 31;
    int te = tid >> 5;
    int row0 = blockIdx.x * 64;

    float4 bias = *(const float4*)(bo + 4 * fe);
    float acc[8][4];
#pragma unroll
    for (int u = 0; u < 8; ++u) {
        acc[u][0] = bias.x; acc[u][1] = bias.y;
        acc[u][2] = bias.z; acc[u][3] = bias.w;
    }
    int rv[8];
#pragma unroll
    for (int u = 0; u < 8; ++u) {
        int r = row0 + te + 8 * u;
        rv[u] = r;
        if (r >= Nrows) rv[u] = Nrows - 1;
    }
    for (int j = 0; j < FD; j += 4) {
        int g = (j + 4 * fe) & 127;
        float4 w0 = *(float4*)(Wl + (4 * fe + 0) * FD + g);
        float4 w1 = *(float4*)(Wl + (4 * fe + 1) * FD + g);
        float4 w2 = *(float4*)(Wl + (4 * fe + 2) * FD + g);
        float4 w3 = *(float4*)(Wl + (4 * fe + 3) * FD + g);
        int hj = j >> 4;
#pragma unroll
        for (int u = 0; u < 8; ++u) {
            float4 a = *(const float4*)(v + (size_t)rv[u] * FD + j);
            float sc = ssum[rv[u] * H + hj];
            a.x *= sc; a.y *= sc; a.z *= sc; a.w *= sc;
            acc[u][0] += a.x * w0.x + a.y * w0.y + a.z * w0.z + a.w * w0.w;
            acc[u][1] += a.x * w1.x + a.y * w1.y + a.z * w1.z + a.w * w1.w;
            acc[u][2] += a.x * w2.x + a.y * w2.y + a.z * w2.z + a.w * w2.w;
            acc[u][3] += a.x * w3.x + a.y * w3.y + a.z * w3.z + a.w * w3.w;
        }
    }
#pragma unroll
    for (int u = 0; u < 8; ++u) {
        int r = row0 + te + 8 * u;
        if (r < Nrows) {
            float4 o;
            o.x = acc[u][0] > 0.f ? acc[u][0] : 0.1f * acc[u][0];
            o.y = acc[u][1] > 0.f ? acc[u][1] : 0.1f * acc[u][1];
            o.z = acc[u][2] > 0.f ? acc[u][2] : 0.1f * acc[u][2];
            o.w = acc[u][3] > 0.f ? acc[u][3] : 0.1f * acc[u][3];
            *(float4*)(out + (size_t)r * FD + 4 * fe) = o;
        }
    }
}

extern "C" void kernel_launch(void* const* d_in, const int* in_sizes, int n_in,
                              void* d_out, int out_size, void* d_ws,
                              size_t ws_size, hipStream_t stream) {
    (void)n_in; (void)out_size; (void)ws_size;
    const float* node_h   = (const float*)d_in[0];
    const float* edge_h   = (const float*)d_in[1];
    const float* distance = (const float*)d_in[2];
    const float* Wq = (const float*)d_in[3];
    const float* bq = (const float*)d_in[4];
    const float* Wk = (const float*)d_in[5];
    const float* bk = (const float*)d_in[6];
    const float* Wv = (const float*)d_in[7];
    const float* bv = (const float*)d_in[8];
    const float* Wo = (const float*)d_in[9];
    const float* bo = (const float*)d_in[10];
    const float* lam = (const float*)d_in[11];
    const int* src = (const int*)d_in[12];
    const int* dst = (const int*)d_in[13];

    int N = in_sizes[0] / FD;
    int E = in_sizes[1] / FD;

    char* ws = (char*)d_ws;
    float* q  = (float*)ws; ws += (size_t)N * FD * 4;
    float* v  = (float*)ws; ws += (size_t)N * FD * 4;
    float* l1 = (float*)ws; ws += (size_t)E * H * 4;
    float* l2 = (float*)ws; ws += (size_t)E * H * 4;
    float* l3 = (float*)ws; ws += (size_t)E * H * 4;
    char* zero_base = ws;
    unsigned* m1 = (unsigned*)ws; ws += (size_t)N * H * 4;
    unsigned* m2 = (unsigned*)ws; ws += (size_t)N * H * 4;
    unsigned* m3 = (unsigned*)ws; ws += (size_t)N * H * 4;
    float* den1 = (float*)ws; ws += (size_t)N * H * 4;
    float* den2 = (float*)ws; ws += (size_t)N * H * 4;
    float* den3 = (float*)ws; ws += (size_t)N * H * 4;
    float* ssum = (float*)ws; ws += (size_t)N * H * 4;

    // zero maxima (uint 0 == "-inf"), denominators, score sums
    hipMemsetAsync(zero_base, 0, (size_t)7 * N * H * 4, stream);

    int nb = (N + 63) / 64;
    proj_kernel<<<nb, 256, 0, stream>>>(node_h, Wq, bq, q, N);
    proj_kernel<<<nb, 256, 0, stream>>>(node_h, Wv, bv, v, N);

    int ebl = (E + 63) / 64;
    edge_kernel<<<ebl, 256, 0, stream>>>(edge_h, Wk, bk, q, src, dst,
                                         l1, l2, l3, m1, m2, m3, E);
    int EH = E * H;
    int sb = (EH + 255) / 256;
    den_kernel<<<sb, 256, 0, stream>>>(l1, l2, l3, m1, m2, m3, dst,
                                       den1, den2, den3, EH);
    score_kernel<<<sb, 256, 0, stream>>>(l1, l2, l3, m1, m2, m3,
                                         den1, den2, den3, dst, distance, lam,
                                         ssum, EH);
    out_kernel<<<nb, 256, 0, stream>>>(v, ssum, Wo, bo, (float*)d_out, N);
}

// Round 2
// 840.468 us; speedup vs baseline: 1.5218x; 1.5218x over previous
//
#include <hip/hip_runtime.h>
#include <math.h>

#define H 8
#define FD 128
#define SCALE 0.25f
#define EPB 128

typedef __attribute__((ext_vector_type(8))) short bf16x8;
typedef __attribute__((ext_vector_type(4))) float f32x4;

__device__ __forceinline__ unsigned short bf_rne(float f) {
    unsigned u = __float_as_uint(f);
    u += 0x7FFFu + ((u >> 16) & 1u);
    return (unsigned short)(u >> 16);
}
__device__ __forceinline__ float bf_to_f(unsigned short s) {
    return __uint_as_float(((unsigned)s) << 16);
}

// ---------------- fused edge kernel: k = bf16-MFMA(edge_h, Wk) + dots -------
// LDS: lW (Wk bf16) + lA (edge tile bf16, reused for k tile). Both stored with
// an 8-col-block XOR swizzle (block' = block ^ (row&7)) so wave64 b128 reads
// are bank-balanced (8 lanes per 4-bank group = BW-optimal).
__global__ __launch_bounds__(256) void edge_kernel(
    const float* __restrict__ eh, const float* __restrict__ Wk,
    const float* __restrict__ bk, const float* __restrict__ q,
    const int* __restrict__ src, const int* __restrict__ dst,
    float* __restrict__ l1, float* __restrict__ l2, float* __restrict__ l3,
    int E) {
    __shared__ unsigned short lW[128 * 128];
    __shared__ unsigned short lA[128 * 128];
    const int t = threadIdx.x;
    const int e0 = blockIdx.x * EPB;

    // stage Wk -> bf16 LDS (row n, col j = Wk[n][j]; B[k=j][n] = Wk[n][j])
#pragma unroll
    for (int i = 0; i < 16; ++i) {
        int flat = i * 256 + t;
        int row = flat >> 5;
        int c4 = flat & 31;
        float4 w = *(const float4*)(Wk + row * 128 + c4 * 4);
        int blk = (c4 >> 1) ^ (row & 7);
        ushort4 p = make_ushort4(bf_rne(w.x), bf_rne(w.y), bf_rne(w.z), bf_rne(w.w));
        *(ushort4*)(lW + row * 128 + blk * 8 + (c4 & 1) * 4) = p;
    }
    // stage edge tile -> bf16 LDS
#pragma unroll
    for (int i = 0; i < 16; ++i) {
        int flat = i * 256 + t;
        int row = flat >> 5;
        int c4 = flat & 31;
        int e = e0 + row;
        if (e >= E) e = E - 1;
        float4 w = *(const float4*)(eh + (size_t)e * 128 + c4 * 4);
        int blk = (c4 >> 1) ^ (row & 7);
        ushort4 p = make_ushort4(bf_rne(w.x), bf_rne(w.y), bf_rne(w.z), bf_rne(w.w));
        *(ushort4*)(lA + row * 128 + blk * 8 + (c4 & 1) * 4) = p;
    }
    __syncthreads();

    const int lane = t & 63;
    const int wv = t >> 6;
    const int lm = lane & 15;   // m (or n) within 16-tile
    const int lq = lane >> 4;   // quad
    const int wm = wv * 32;     // wave's edge-row base

    // A fragments: A[m=lm][k = (s*4+lq)*8 + j]
    bf16x8 a[2][4];
#pragma unroll
    for (int mt = 0; mt < 2; ++mt)
#pragma unroll
        for (int s = 0; s < 4; ++s) {
            int row = wm + mt * 16 + lm;
            int swb = (s * 4 + lq) ^ (row & 7);
            a[mt][s] = *(const bf16x8*)(lA + row * 128 + swb * 8);
        }

    // acc init with bias bk[n] (same col n for all 4 regs of a tile)
    f32x4 acc[2][8];
#pragma unroll
    for (int nt = 0; nt < 8; ++nt) {
        float b = bk[nt * 16 + lm];
#pragma unroll
        for (int mt = 0; mt < 2; ++mt) {
            acc[mt][nt][0] = b; acc[mt][nt][1] = b;
            acc[mt][nt][2] = b; acc[mt][nt][3] = b;
        }
    }
#pragma unroll
    for (int s = 0; s < 4; ++s) {
#pragma unroll
        for (int nt = 0; nt < 8; ++nt) {
            int row = nt * 16 + lm;
            int swb = (s * 4 + lq) ^ (row & 7);
            bf16x8 bf = *(const bf16x8*)(lW + row * 128 + swb * 8);
#pragma unroll
            for (int mt = 0; mt < 2; ++mt)
                acc[mt][nt] = __builtin_amdgcn_mfma_f32_16x16x32_bf16(
                    a[mt][s], bf, acc[mt][nt], 0, 0, 0);
        }
    }
    __syncthreads();
    // write k tile (bf16) back into lA, same swizzle.
    // C layout: col n = lm, row m = lq*4 + r (within tile)
#pragma unroll
    for (int mt = 0; mt < 2; ++mt)
#pragma unroll
        for (int nt = 0; nt < 8; ++nt)
#pragma unroll
            for (int r = 0; r < 4; ++r) {
                int m = wm + mt * 16 + lq * 4 + r;
                int n = nt * 16 + lm;
                int swb = (n >> 3) ^ (m & 7);
                lA[m * 128 + swb * 8 + (n & 7)] = bf_rne(acc[mt][nt][r]);
            }
    __syncthreads();

    // epilogue: one lane per (edge, head)
#pragma unroll
    for (int i = 0; i < 4; ++i) {
        int p = i * 256 + t;
        int el = p >> 3, h = p & 7;
        int e = e0 + el;
        if (e >= E) continue;
        int si = src[e], di = dst[e];
        const float* qsp = q + (size_t)si * FD + h * 16;
        const float* qdp = q + (size_t)di * FD + h * 16;
        float4 s0 = *(const float4*)(qsp);
        float4 s1 = *(const float4*)(qsp + 4);
        float4 s2 = *(const float4*)(qsp + 8);
        float4 s3 = *(const float4*)(qsp + 12);
        float4 d0 = *(const float4*)(qdp);
        float4 d1 = *(const float4*)(qdp + 4);
        float4 d2 = *(const float4*)(qdp + 8);
        float4 d3 = *(const float4*)(qdp + 12);
        int swb0 = (2 * h) ^ (el & 7);
        int swb1 = (2 * h + 1) ^ (el & 7);
        bf16x8 k0 = *(const bf16x8*)(lA + el * 128 + swb0 * 8);
        bf16x8 k1 = *(const bf16x8*)(lA + el * 128 + swb1 * 8);
        float qsv[16] = { s0.x, s0.y, s0.z, s0.w, s1.x, s1.y, s1.z, s1.w,
                          s2.x, s2.y, s2.z, s2.w, s3.x, s3.y, s3.z, s3.w };
        float qdv[16] = { d0.x, d0.y, d0.z, d0.w, d1.x, d1.y, d1.z, d1.w,
                          d2.x, d2.y, d2.z, d2.w, d3.x, d3.y, d3.z, d3.w };
        float pin = 0.f, pot = 0.f, pdg = 0.f;
#pragma unroll
        for (int j = 0; j < 8; ++j) {
            float kf = bf_to_f((unsigned short)k0[j]);
            pin += qsv[j] * kf; pot += qdv[j] * kf; pdg += qsv[j] * qdv[j];
        }
#pragma unroll
        for (int j = 0; j < 8; ++j) {
            float kf = bf_to_f((unsigned short)k1[j]);
            pin += qsv[8 + j] * kf; pot += qdv[8 + j] * kf;
            pdg += qsv[8 + j] * qdv[8 + j];
        }
        size_t gi = (size_t)e * H + h;
        l1[gi] = pin * SCALE;
        l2[gi] = pot * SCALE;
        l3[gi] = pdg * SCALE;
    }
}

// ---------------- softmax passes (no max-shift: logits are O(6) max) -------
__global__ __launch_bounds__(256) void den_kernel(
    float* __restrict__ l1, float* __restrict__ l2, float* __restrict__ l3,
    const int* __restrict__ dst, const float* __restrict__ distance,
    const float* __restrict__ lam, float* __restrict__ den1,
    float* __restrict__ den2, float* __restrict__ den3,
    float* __restrict__ att, int EH) {
    int idx = blockIdx.x * 256 + threadIdx.x;
    if (idx >= EH) return;
    int e = idx >> 3, h = idx & 7;
    int nb = dst[e] * H + h;
    float x1 = __expf(l1[idx]); l1[idx] = x1; atomicAdd(den1 + nb, x1);
    float x2 = __expf(l2[idx]); l2[idx] = x2; atomicAdd(den2 + nb, x2);
    float x3 = __expf(l3[idx]); l3[idx] = x3; atomicAdd(den3 + nb, x3);
    if (h == 0) att[e] = __powf(distance[e], lam[0]);
}

__global__ __launch_bounds__(256) void recip_kernel(
    float* __restrict__ den1, float* __restrict__ den2,
    float* __restrict__ den3, int NH) {
    int idx = blockIdx.x * 256 + threadIdx.x;
    if (idx >= NH) return;
    float d1 = den1[idx]; den1[idx] = (d1 == 0.f) ? 0.f : 1.f / d1;
    float d2 = den2[idx]; den2[idx] = (d2 == 0.f) ? 0.f : 1.f / d2;
    float d3 = den3[idx]; den3[idx] = (d3 == 0.f) ? 0.f : 1.f / d3;
}

__global__ __launch_bounds__(256) void score_kernel(
    const float* __restrict__ l1, const float* __restrict__ l2,
    const float* __restrict__ l3, const float* __restrict__ den1,
    const float* __restrict__ den2, const float* __restrict__ den3,
    const int* __restrict__ dst, const float* __restrict__ att,
    float* __restrict__ ssum, int EH) {
    int idx = blockIdx.x * 256 + threadIdx.x;
    if (idx >= EH) return;
    int e = idx >> 3, h = idx & 7;
    int nb = dst[e] * H + h;
    float sc = (l1[idx] * den1[nb] + l2[idx] * den2[nb] + l3[idx] * den3[nb]) *
               att[e];
    atomicAdd(ssum + nb, sc);
}

// ---------------- dense projections (fp32 vector path, round-1) ------------
__device__ __forceinline__ void load_w_lds(const float* __restrict__ W,
                                           float* Wl, int tid) {
    for (int x = tid; x < (FD * FD) / 4; x += 256) {
        int idx4 = x << 2;
        int i = idx4 >> 7;
        int j = idx4 & 127;
        float4 w = *(const float4*)(W + idx4);
        int col = (j + ((i >> 2) << 2)) & 127;
        *(float4*)(Wl + i * FD + col) = w;
    }
}

__global__ __launch_bounds__(256) void proj_kernel(
    const float* __restrict__ X, const float* __restrict__ W,
    const float* __restrict__ b, float* __restrict__ out, int Nrows) {
    __shared__ float Wl[FD * FD];
    int tid = threadIdx.x;
    load_w_lds(W, Wl, tid);
    __syncthreads();

    int fe = tid & 31;
    int te = tid >> 5;
    int row0 = blockIdx.x * 64;

    float4 bias = *(const float4*)(b + 4 * fe);
    float acc[8][4];
#pragma unroll
    for (int u = 0; u < 8; ++u) {
        acc[u][0] = bias.x; acc[u][1] = bias.y;
        acc[u][2] = bias.z; acc[u][3] = bias.w;
    }
    const float* Ar[8];
#pragma unroll
    for (int u = 0; u < 8; ++u) {
        int r = row0 + te + 8 * u;
        if (r >= Nrows) r = Nrows - 1;
        Ar[u] = X + (size_t)r * FD;
    }
    for (int j = 0; j < FD; j += 4) {
        int g = (j + 4 * fe) & 127;
        float4 w0 = *(float4*)(Wl + (4 * fe + 0) * FD + g);
        float4 w1 = *(float4*)(Wl + (4 * fe + 1) * FD + g);
        float4 w2 = *(float4*)(Wl + (4 * fe + 2) * FD + g);
        float4 w3 = *(float4*)(Wl + (4 * fe + 3) * FD + g);
#pragma unroll
        for (int u = 0; u < 8; ++u) {
            float4 a = *(const float4*)(Ar[u] + j);
            acc[u][0] += a.x * w0.x + a.y * w0.y + a.z * w0.z + a.w * w0.w;
            acc[u][1] += a.x * w1.x + a.y * w1.y + a.z * w1.z + a.w * w1.w;
            acc[u][2] += a.x * w2.x + a.y * w2.y + a.z * w2.z + a.w * w2.w;
            acc[u][3] += a.x * w3.x + a.y * w3.y + a.z * w3.z + a.w * w3.w;
        }
    }
#pragma unroll
    for (int u = 0; u < 8; ++u) {
        int r = row0 + te + 8 * u;
        if (r < Nrows) {
            float4 o;
            o.x = acc[u][0]; o.y = acc[u][1]; o.z = acc[u][2]; o.w = acc[u][3];
            *(float4*)(out + (size_t)r * FD + 4 * fe) = o;
        }
    }
}

__global__ __launch_bounds__(256) void out_kernel(
    const float* __restrict__ v, const float* __restrict__ ssum,
    const float* __restrict__ Wo, const float* __restrict__ bo,
    float* __restrict__ out, int Nrows) {
    __shared__ float Wl[FD * FD];
    int tid = threadIdx.x;
    load_w_lds(Wo, Wl, tid);
    __syncthreads();

    int fe = tid & 31;
    int te = tid >> 5;
    int row0 = blockIdx.x * 64;

    float4 bias = *(const float4*)(bo + 4 * fe);
    float acc[8][4];
#pragma unroll
    for (int u = 0; u < 8; ++u) {
        acc[u][0] = bias.x; acc[u][1] = bias.y;
        acc[u][2] = bias.z; acc[u][3] = bias.w;
    }
    int rv[8];
#pragma unroll
    for (int u = 0; u < 8; ++u) {
        int r = row0 + te + 8 * u;
        rv[u] = (r >= Nrows) ? (Nrows - 1) : r;
    }
    for (int j = 0; j < FD; j += 4) {
        int g = (j + 4 * fe) & 127;
        float4 w0 = *(float4*)(Wl + (4 * fe + 0) * FD + g);
        float4 w1 = *(float4*)(Wl + (4 * fe + 1) * FD + g);
        float4 w2 = *(float4*)(Wl + (4 * fe + 2) * FD + g);
        float4 w3 = *(float4*)(Wl + (4 * fe + 3) * FD + g);
        int hj = j >> 4;
#pragma unroll
        for (int u = 0; u < 8; ++u) {
            float4 a = *(const float4*)(v + (size_t)rv[u] * FD + j);
            float sc = ssum[rv[u] * H + hj];
            a.x *= sc; a.y *= sc; a.z *= sc; a.w *= sc;
            acc[u][0] += a.x * w0.x + a.y * w0.y + a.z * w0.z + a.w * w0.w;
            acc[u][1] += a.x * w1.x + a.y * w1.y + a.z * w1.z + a.w * w1.w;
            acc[u][2] += a.x * w2.x + a.y * w2.y + a.z * w2.z + a.w * w2.w;
            acc[u][3] += a.x * w3.x + a.y * w3.y + a.z * w3.z + a.w * w3.w;
        }
    }
#pragma unroll
    for (int u = 0; u < 8; ++u) {
        int r = row0 + te + 8 * u;
        if (r < Nrows) {
            float4 o;
            o.x = acc[u][0] > 0.f ? acc[u][0] : 0.1f * acc[u][0];
            o.y = acc[u][1] > 0.f ? acc[u][1] : 0.1f * acc[u][1];
            o.z = acc[u][2] > 0.f ? acc[u][2] : 0.1f * acc[u][2];
            o.w = acc[u][3] > 0.f ? acc[u][3] : 0.1f * acc[u][3];
            *(float4*)(out + (size_t)r * FD + 4 * fe) = o;
        }
    }
}

extern "C" void kernel_launch(void* const* d_in, const int* in_sizes, int n_in,
                              void* d_out, int out_size, void* d_ws,
                              size_t ws_size, hipStream_t stream) {
    (void)n_in; (void)out_size; (void)ws_size;
    const float* node_h   = (const float*)d_in[0];
    const float* edge_h   = (const float*)d_in[1];
    const float* distance = (const float*)d_in[2];
    const float* Wq = (const float*)d_in[3];
    const float* bq = (const float*)d_in[4];
    const float* Wk = (const float*)d_in[5];
    const float* bk = (const float*)d_in[6];
    const float* Wv = (const float*)d_in[7];
    const float* bv = (const float*)d_in[8];
    const float* Wo = (const float*)d_in[9];
    const float* bo = (const float*)d_in[10];
    const float* lam = (const float*)d_in[11];
    const int* src = (const int*)d_in[12];
    const int* dst = (const int*)d_in[13];

    int N = in_sizes[0] / FD;
    int E = in_sizes[1] / FD;

    char* ws = (char*)d_ws;
    float* q   = (float*)ws; ws += (size_t)N * FD * 4;
    float* v   = (float*)ws; ws += (size_t)N * FD * 4;
    float* l1  = (float*)ws; ws += (size_t)E * H * 4;
    float* l2  = (float*)ws; ws += (size_t)E * H * 4;
    float* l3  = (float*)ws; ws += (size_t)E * H * 4;
    float* att = (float*)ws; ws += (size_t)E * 4;
    char* zero_base = ws;
    float* den1 = (float*)ws; ws += (size_t)N * H * 4;
    float* den2 = (float*)ws; ws += (size_t)N * H * 4;
    float* den3 = (float*)ws; ws += (size_t)N * H * 4;
    float* ssum = (float*)ws; ws += (size_t)N * H * 4;

    hipMemsetAsync(zero_base, 0, (size_t)4 * N * H * 4, stream);

    int nb = (N + 63) / 64;
    proj_kernel<<<nb, 256, 0, stream>>>(node_h, Wq, bq, q, N);
    proj_kernel<<<nb, 256, 0, stream>>>(node_h, Wv, bv, v, N);

    int ebl = (E + EPB - 1) / EPB;
    edge_kernel<<<ebl, 256, 0, stream>>>(edge_h, Wk, bk, q, src, dst,
                                         l1, l2, l3, E);
    int EH = E * H;
    int sb = (EH + 255) / 256;
    den_kernel<<<sb, 256, 0, stream>>>(l1, l2, l3, dst, distance, lam,
                                       den1, den2, den3, att, EH);
    int NH = N * H;
    recip_kernel<<<(NH + 255) / 256, 256, 0, stream>>>(den1, den2, den3, NH);
    score_kernel<<<sb, 256, 0, stream>>>(l1, l2, l3, den1, den2, den3,
                                         dst, att, ssum, EH);
    out_kernel<<<nb, 256, 0, stream>>>(v, ssum, Wo, bo, (float*)d_out, N);
}

// Round 3
// 676.399 us; speedup vs baseline: 1.8909x; 1.2426x over previous
//
#include <hip/hip_runtime.h>
#include <math.h>

#define H 8
#define FD 128
#define SCALE 0.25f

typedef __attribute__((ext_vector_type(8))) short bf16x8;
typedef __attribute__((ext_vector_type(4))) float f32x4;

__device__ __forceinline__ unsigned short bf_rne(float f) {
    unsigned u = __float_as_uint(f);
    u += 0x7FFFu + ((u >> 16) & 1u);
    return (unsigned short)(u >> 16);
}
__device__ __forceinline__ float bf_to_f(unsigned short s) {
    return __uint_as_float(((unsigned)s) << 16);
}
__device__ __forceinline__ bf16x8 cvt8(const float* __restrict__ p) {
    float4 a = *(const float4*)p;
    float4 b = *(const float4*)(p + 4);
    bf16x8 r;
    r[0] = bf_rne(a.x); r[1] = bf_rne(a.y); r[2] = bf_rne(a.z); r[3] = bf_rne(a.w);
    r[4] = bf_rne(b.x); r[5] = bf_rne(b.y); r[6] = bf_rne(b.z); r[7] = bf_rne(b.w);
    return r;
}

// ---- one-time weight conversion fp32 -> bf16 (4 x 128x128) ----
__global__ __launch_bounds__(256) void prep_kernel(
    const float* __restrict__ Wq, const float* __restrict__ Wk,
    const float* __restrict__ Wv, const float* __restrict__ Wo,
    unsigned short* __restrict__ oq, unsigned short* __restrict__ ok,
    unsigned short* __restrict__ ov, unsigned short* __restrict__ oo) {
    int i = blockIdx.x * 256 + threadIdx.x;  // 0..4095 float4 groups
    const float* src[4] = {Wq, Wk, Wv, Wo};
    unsigned short* dstp[4] = {oq, ok, ov, oo};
#pragma unroll
    for (int m = 0; m < 4; ++m) {
        float4 w = ((const float4*)src[m])[i];
        ushort4 p = make_ushort4(bf_rne(w.x), bf_rne(w.y), bf_rne(w.z), bf_rne(w.w));
        *(ushort4*)(dstp[m] + i * 4) = p;
    }
}

// ---- fused q (bf16 out) + v (fp32 out) projection, MFMA ----
__global__ __launch_bounds__(256) void qv_kernel(
    const float* __restrict__ X, const unsigned short* __restrict__ Wqb,
    const unsigned short* __restrict__ Wvb, const float* __restrict__ bq,
    const float* __restrict__ bv, unsigned short* __restrict__ qb,
    float* __restrict__ v, int Nrows) {
    const int t = threadIdx.x;
    const int lane = t & 63, wid = t >> 6;
    const int lm = lane & 15, lq = lane >> 4;
    const int r0 = blockIdx.x * 128 + wid * 32;

    bf16x8 a[2][4];
#pragma unroll
    for (int mt = 0; mt < 2; ++mt)
#pragma unroll
        for (int s = 0; s < 4; ++s) {
            int r = r0 + mt * 16 + lm;
            if (r >= Nrows) r = Nrows - 1;
            a[mt][s] = cvt8(X + (size_t)r * FD + s * 32 + lq * 8);
        }
#pragma unroll
    for (int g = 0; g < 2; ++g) {
        const unsigned short* Wb = g ? Wvb : Wqb;
        const float* bias = g ? bv : bq;
        f32x4 acc[2][8];
#pragma unroll
        for (int nt = 0; nt < 8; ++nt) {
            float b = bias[nt * 16 + lm];
#pragma unroll
            for (int mt = 0; mt < 2; ++mt) {
                acc[mt][nt][0] = b; acc[mt][nt][1] = b;
                acc[mt][nt][2] = b; acc[mt][nt][3] = b;
            }
        }
#pragma unroll
        for (int s = 0; s < 4; ++s)
#pragma unroll
            for (int nt = 0; nt < 8; ++nt) {
                bf16x8 bf = *(const bf16x8*)(Wb + (nt * 16 + lm) * FD + s * 32 + lq * 8);
#pragma unroll
                for (int mt = 0; mt < 2; ++mt)
                    acc[mt][nt] = __builtin_amdgcn_mfma_f32_16x16x32_bf16(
                        a[mt][s], bf, acc[mt][nt], 0, 0, 0);
            }
#pragma unroll
        for (int mt = 0; mt < 2; ++mt)
#pragma unroll
            for (int nt = 0; nt < 8; ++nt)
#pragma unroll
                for (int r = 0; r < 4; ++r) {
                    int row = r0 + mt * 16 + lq * 4 + r;
                    if (row >= Nrows) continue;
                    int col = nt * 16 + lm;
                    if (g == 0)
                        qb[(size_t)row * FD + col] = bf_rne(acc[mt][nt][r]);
                    else
                        v[(size_t)row * FD + col] = acc[mt][nt][r];
                }
    }
}

// ---- fused edge kernel: k = MFMA(edge_h, Wk), dots, exp, 6 atomic sums ----
__global__ __launch_bounds__(256) void edge_kernel(
    const float* __restrict__ eh, const unsigned short* __restrict__ Wkb,
    const float* __restrict__ bk, const unsigned short* __restrict__ qb,
    const int* __restrict__ src, const int* __restrict__ dst,
    const float* __restrict__ distance, const float* __restrict__ lam,
    float* __restrict__ den1, float* __restrict__ den2,
    float* __restrict__ den3, float* __restrict__ sc1,
    float* __restrict__ sc2, float* __restrict__ sc3, int E) {
    __shared__ unsigned short lK[128 * 128];  // k tile, bf16, XOR-swizzled
    const int t = threadIdx.x;
    const int e0 = blockIdx.x * 128;
    const int lane = t & 63, wid = t >> 6;
    const int lm = lane & 15, lq = lane >> 4;
    const int wm = wid * 32;

    bf16x8 a[2][4];
#pragma unroll
    for (int mt = 0; mt < 2; ++mt)
#pragma unroll
        for (int s = 0; s < 4; ++s) {
            int e = e0 + wm + mt * 16 + lm;
            if (e >= E) e = E - 1;
            a[mt][s] = cvt8(eh + (size_t)e * FD + s * 32 + lq * 8);
        }
    f32x4 acc[2][8];
#pragma unroll
    for (int nt = 0; nt < 8; ++nt) {
        float b = bk[nt * 16 + lm];
#pragma unroll
        for (int mt = 0; mt < 2; ++mt) {
            acc[mt][nt][0] = b; acc[mt][nt][1] = b;
            acc[mt][nt][2] = b; acc[mt][nt][3] = b;
        }
    }
#pragma unroll
    for (int s = 0; s < 4; ++s)
#pragma unroll
        for (int nt = 0; nt < 8; ++nt) {
            bf16x8 bf = *(const bf16x8*)(Wkb + (nt * 16 + lm) * FD + s * 32 + lq * 8);
#pragma unroll
            for (int mt = 0; mt < 2; ++mt)
                acc[mt][nt] = __builtin_amdgcn_mfma_f32_16x16x32_bf16(
                    a[mt][s], bf, acc[mt][nt], 0, 0, 0);
        }
    // k tile -> LDS (bf16), swizzle: block' = (n>>3) ^ (m&7)
#pragma unroll
    for (int mt = 0; mt < 2; ++mt)
#pragma unroll
        for (int nt = 0; nt < 8; ++nt)
#pragma unroll
            for (int r = 0; r < 4; ++r) {
                int m = wm + mt * 16 + lq * 4 + r;
                int n = nt * 16 + lm;
                int swb = (n >> 3) ^ (m & 7);
                lK[m * 128 + swb * 8 + (n & 7)] = bf_rne(acc[mt][nt][r]);
            }
    __syncthreads();

    const float lamv = lam[0];
#pragma unroll
    for (int i = 0; i < 4; ++i) {
        int p = i * 256 + t;
        int el = p >> 3, h = p & 7;
        int e = e0 + el;
        if (e >= E) continue;
        int si = src[e], di = dst[e];
        const unsigned short* qsp = qb + (size_t)si * FD + h * 16;
        const unsigned short* qdp = qb + (size_t)di * FD + h * 16;
        bf16x8 qs0 = *(const bf16x8*)qsp;
        bf16x8 qs1 = *(const bf16x8*)(qsp + 8);
        bf16x8 qd0 = *(const bf16x8*)qdp;
        bf16x8 qd1 = *(const bf16x8*)(qdp + 8);
        int swb0 = (2 * h) ^ (el & 7), swb1 = (2 * h + 1) ^ (el & 7);
        bf16x8 k0 = *(const bf16x8*)(lK + el * 128 + swb0 * 8);
        bf16x8 k1 = *(const bf16x8*)(lK + el * 128 + swb1 * 8);
        float pin = 0.f, pot = 0.f, pdg = 0.f;
#pragma unroll
        for (int j = 0; j < 8; ++j) {
            float qsf = bf_to_f((unsigned short)qs0[j]);
            float qdf = bf_to_f((unsigned short)qd0[j]);
            float kf = bf_to_f((unsigned short)k0[j]);
            pin += qsf * kf; pot += qdf * kf; pdg += qsf * qdf;
        }
#pragma unroll
        for (int j = 0; j < 8; ++j) {
            float qsf = bf_to_f((unsigned short)qs1[j]);
            float qdf = bf_to_f((unsigned short)qd1[j]);
            float kf = bf_to_f((unsigned short)k1[j]);
            pin += qsf * kf; pot += qdf * kf; pdg += qsf * qdf;
        }
        float att = __expf(lamv * __logf(distance[e]));
        float e1 = __expf(pin * SCALE);
        float e2 = __expf(pot * SCALE);
        float e3 = __expf(pdg * SCALE);
        int nb = di * H + h;
        atomicAdd(den1 + nb, e1); atomicAdd(sc1 + nb, e1 * att);
        atomicAdd(den2 + nb, e2); atomicAdd(sc2 + nb, e2 * att);
        atomicAdd(den3 + nb, e3); atomicAdd(sc3 + nb, e3 * att);
    }
}

// ---- per (node,head): ssum = s1/d1 + s2/d2 + s3/d3 ----
__global__ __launch_bounds__(256) void combine_kernel(
    const float* __restrict__ den1, const float* __restrict__ den2,
    const float* __restrict__ den3, const float* __restrict__ sc1,
    const float* __restrict__ sc2, const float* __restrict__ sc3,
    float* __restrict__ ssum, int NH) {
    int i = blockIdx.x * 256 + threadIdx.x;
    if (i >= NH) return;
    float r = 0.f;
    float d1 = den1[i]; if (d1 != 0.f) r += sc1[i] / d1;
    float d2 = den2[i]; if (d2 != 0.f) r += sc2[i] / d2;
    float d3 = den3[i]; if (d3 != 0.f) r += sc3[i] / d3;
    ssum[i] = r;
}

// ---- out = leaky_relu( (ssum*v) @ Wo.T + bo ), MFMA ----
__global__ __launch_bounds__(256) void out_kernel(
    const float* __restrict__ v, const float* __restrict__ ssum,
    const unsigned short* __restrict__ Wob, const float* __restrict__ bo,
    float* __restrict__ out, int Nrows) {
    const int t = threadIdx.x;
    const int lane = t & 63, wid = t >> 6;
    const int lm = lane & 15, lq = lane >> 4;
    const int r0 = blockIdx.x * 128 + wid * 32;

    bf16x8 a[2][4];
#pragma unroll
    for (int mt = 0; mt < 2; ++mt)
#pragma unroll
        for (int s = 0; s < 4; ++s) {
            int r = r0 + mt * 16 + lm;
            if (r >= Nrows) r = Nrows - 1;
            int k0 = s * 32 + lq * 8;
            float sc = ssum[r * H + (k0 >> 4)];
            const float* p = v + (size_t)r * FD + k0;
            float4 x = *(const float4*)p;
            float4 y = *(const float4*)(p + 4);
            bf16x8 f;
            f[0] = bf_rne(x.x * sc); f[1] = bf_rne(x.y * sc);
            f[2] = bf_rne(x.z * sc); f[3] = bf_rne(x.w * sc);
            f[4] = bf_rne(y.x * sc); f[5] = bf_rne(y.y * sc);
            f[6] = bf_rne(y.z * sc); f[7] = bf_rne(y.w * sc);
            a[mt][s] = f;
        }
    f32x4 acc[2][8];
#pragma unroll
    for (int nt = 0; nt < 8; ++nt) {
        float b = bo[nt * 16 + lm];
#pragma unroll
        for (int mt = 0; mt < 2; ++mt) {
            acc[mt][nt][0] = b; acc[mt][nt][1] = b;
            acc[mt][nt][2] = b; acc[mt][nt][3] = b;
        }
    }
#pragma unroll
    for (int s = 0; s < 4; ++s)
#pragma unroll
        for (int nt = 0; nt < 8; ++nt) {
            bf16x8 bf = *(const bf16x8*)(Wob + (nt * 16 + lm) * FD + s * 32 + lq * 8);
#pragma unroll
            for (int mt = 0; mt < 2; ++mt)
                acc[mt][nt] = __builtin_amdgcn_mfma_f32_16x16x32_bf16(
                    a[mt][s], bf, acc[mt][nt], 0, 0, 0);
        }
#pragma unroll
    for (int mt = 0; mt < 2; ++mt)
#pragma unroll
        for (int nt = 0; nt < 8; ++nt)
#pragma unroll
            for (int r = 0; r < 4; ++r) {
                int row = r0 + mt * 16 + lq * 4 + r;
                if (row >= Nrows) continue;
                int col = nt * 16 + lm;
                float x = acc[mt][nt][r];
                out[(size_t)row * FD + col] = x > 0.f ? x : 0.1f * x;
            }
}

extern "C" void kernel_launch(void* const* d_in, const int* in_sizes, int n_in,
                              void* d_out, int out_size, void* d_ws,
                              size_t ws_size, hipStream_t stream) {
    (void)n_in; (void)out_size; (void)ws_size;
    const float* node_h   = (const float*)d_in[0];
    const float* edge_h   = (const float*)d_in[1];
    const float* distance = (const float*)d_in[2];
    const float* Wq = (const float*)d_in[3];
    const float* bq = (const float*)d_in[4];
    const float* Wk = (const float*)d_in[5];
    const float* bk = (const float*)d_in[6];
    const float* Wv = (const float*)d_in[7];
    const float* bv = (const float*)d_in[8];
    const float* Wo = (const float*)d_in[9];
    const float* bo = (const float*)d_in[10];
    const float* lam = (const float*)d_in[11];
    const int* src = (const int*)d_in[12];
    const int* dst = (const int*)d_in[13];

    int N = in_sizes[0] / FD;
    int E = in_sizes[1] / FD;
    int NH = N * H;

    char* ws = (char*)d_ws;
    unsigned short* Wqb = (unsigned short*)ws; ws += FD * FD * 2;
    unsigned short* Wkb = (unsigned short*)ws; ws += FD * FD * 2;
    unsigned short* Wvb = (unsigned short*)ws; ws += FD * FD * 2;
    unsigned short* Wob = (unsigned short*)ws; ws += FD * FD * 2;
    unsigned short* qb  = (unsigned short*)ws; ws += (size_t)N * FD * 2;
    float* v    = (float*)ws; ws += (size_t)N * FD * 4;
    char* zero_base = ws;
    float* den1 = (float*)ws; ws += (size_t)NH * 4;
    float* den2 = (float*)ws; ws += (size_t)NH * 4;
    float* den3 = (float*)ws; ws += (size_t)NH * 4;
    float* sc1  = (float*)ws; ws += (size_t)NH * 4;
    float* sc2  = (float*)ws; ws += (size_t)NH * 4;
    float* sc3  = (float*)ws; ws += (size_t)NH * 4;
    float* ssum = (float*)ws; ws += (size_t)NH * 4;

    hipMemsetAsync(zero_base, 0, (size_t)6 * NH * 4, stream);

    prep_kernel<<<16, 256, 0, stream>>>(Wq, Wk, Wv, Wo, Wqb, Wkb, Wvb, Wob);

    int nb = (N + 127) / 128;
    qv_kernel<<<nb, 256, 0, stream>>>(node_h, Wqb, Wvb, bq, bv, qb, v, N);

    int ebl = (E + 127) / 128;
    edge_kernel<<<ebl, 256, 0, stream>>>(edge_h, Wkb, bk, qb, src, dst,
                                         distance, lam,
                                         den1, den2, den3, sc1, sc2, sc3, E);

    combine_kernel<<<(NH + 255) / 256, 256, 0, stream>>>(
        den1, den2, den3, sc1, sc2, sc3, ssum, NH);

    out_kernel<<<nb, 256, 0, stream>>>(v, ssum, Wob, bo, (float*)d_out, N);
}